// Round 3
// baseline (51.537 us; speedup 1.0000x reference)
//
#include <hip/hip_runtime.h>
#include <math.h>

#define BB 2
#define C_IN 32
#define HH 64
#define WW 64
#define J (HH*WW)        // 4096
#define HID 64
#define C_OUT 32
#define S 256
#define JT 8             // j's per block: 4 waves x 2 j-halves

// gelu(x) ~= x * sigmoid(A*x + B*x^3)   (tanh-form gelu rewritten)
// exp2 domain: A = 2*sqrt(2/pi)*log2(e), B = A*0.044715
#define GELU_A 2.3022043f
#define GELU_B 0.10294306f

// u[b,s,hid] = b1[hid] - sx*W1[0,hid] - sy*W1[1,hid] + sum_c vp[b,idx,c]*W1[2+c,hid]
__global__ __launch_bounds__(64) void nystrom_prep(const float* __restrict__ v,
    const int* __restrict__ indices, const float* __restrict__ W1,
    const float* __restrict__ b1, float* __restrict__ u)
{
    int bs  = blockIdx.x;            // 0..B*S-1
    int b   = bs / S;
    int s   = bs % S;
    int hid = threadIdx.x;           // 0..63
    int idx = indices[s];
    float sx = (float)(idx & (WW - 1)) * (1.0f / (WW - 1));
    float sy = (float)(idx >> 6)       * (1.0f / (HH - 1));
    float acc = b1[hid] - sx * W1[hid] - sy * W1[HID + hid];
    const float* vb = v + (size_t)b * C_IN * J + idx;
    #pragma unroll
    for (int c = 0; c < C_IN; ++c) {
        acc += vb[c * J] * W1[(2 + c) * HID + hid];
    }
    u[((size_t)b * S + s) * HID + hid] = acc;
}

__global__ __launch_bounds__(256) void nystrom_main(const float* __restrict__ u,
    const float* __restrict__ W1, const float* __restrict__ W2,
    const float* __restrict__ b2, float* __restrict__ out)
{
    __shared__ float G[JT][HID + 1];   // ~2 KB, epilogue only
    int tid  = threadIdx.x;
    int blk  = blockIdx.x;             // 0..B*(J/JT)-1
    int b    = blk / (J / JT);
    int j0   = (blk % (J / JT)) * JT;
    int w    = tid >> 6;               // wave 0..3
    int lane = tid & 63;
    int jj   = lane >> 5;              // which j of the wave's pair
    int hp   = lane & 31;              // hid-pair index
    int h    = hp * 2;
    int jl   = w * 2 + jj;             // 0..7 within block
    int j    = j0 + jl;

    float xj  = (float)(j & (WW - 1)) * (1.0f / (WW - 1));
    float yj  = (float)(j >> 6)       * (1.0f / (HH - 1));
    float cj0 = xj * W1[h]     + yj * W1[HID + h];
    float cj1 = xj * W1[h + 1] + yj * W1[HID + h + 1];

    const float2* up = (const float2*)(u + (size_t)b * S * HID) + hp;
    float acc0 = 0.0f, acc1 = 0.0f;
    #pragma unroll 4
    for (int s = 0; s < S; ++s) {
        float2 uv = up[s * 32];
        // chain 0
        float x0 = cj0 + uv.x;
        float p0 = __builtin_fmaf(-GELU_B, x0 * x0, -GELU_A);
        float e0 = __builtin_amdgcn_exp2f(p0 * x0);      // exp2(-t)
        acc0 = __builtin_fmaf(x0, __builtin_amdgcn_rcpf(e0 + 1.0f), acc0);
        // chain 1
        float x1 = cj1 + uv.y;
        float p1 = __builtin_fmaf(-GELU_B, x1 * x1, -GELU_A);
        float e1 = __builtin_amdgcn_exp2f(p1 * x1);
        acc1 = __builtin_fmaf(x1, __builtin_amdgcn_rcpf(e1 + 1.0f), acc1);
    }

    G[jl][h]     = acc0;
    G[jl][h + 1] = acc1;
    __syncthreads();

    // epilogue: out[b,co,j0+jt] = (1/S) * sum_h G[jt][h]*W2[h,co] + b2[co]
    {
        int jt = tid & (JT - 1);       // 0..7
        int co = tid >> 3;             // 0..31
        float sum = 0.0f;
        #pragma unroll
        for (int hh = 0; hh < HID; ++hh) {
            sum += G[jt][hh] * W2[hh * C_OUT + co];
        }
        out[(size_t)b * C_OUT * J + (size_t)co * J + j0 + jt] = sum * (1.0f / S) + b2[co];
    }
}

extern "C" void kernel_launch(void* const* d_in, const int* in_sizes, int n_in,
                              void* d_out, int out_size, void* d_ws, size_t ws_size,
                              hipStream_t stream) {
    const float* v       = (const float*)d_in[0];
    const int*   indices = (const int*)  d_in[1];
    const float* W1      = (const float*)d_in[2];
    const float* b1      = (const float*)d_in[3];
    const float* W2      = (const float*)d_in[4];
    const float* b2      = (const float*)d_in[5];
    float* out = (float*)d_out;
    float* u   = (float*)d_ws;   // B*S*HID*4 = 128 KB

    hipLaunchKernelGGL(nystrom_prep, dim3(BB * S), dim3(64), 0, stream,
                       v, indices, W1, b1, u);
    hipLaunchKernelGGL(nystrom_main, dim3(BB * (J / JT)), dim3(256), 0, stream,
                       u, W1, W2, b2, out);
}

// Round 4
// 27.948 us; speedup vs baseline: 1.8440x; 1.8440x over previous
//
#include <hip/hip_runtime.h>
#include <math.h>

#define BB 2
#define C_IN 32
#define HH 64
#define WW 64
#define J (HH*WW)        // 4096
#define HID 64
#define C_OUT 32
#define S 256
#define TN 256           // table knots per (b,h)
#define JT3 32           // j's per eval block

// gelu(x) ~= x * sigmoid(A*x + B*x^3)  (tanh-form gelu, exp2 domain)
#define GELU_A 2.3022043f
#define GELU_B 0.10294306f

// ---------- kernel 1: u[b,s,hid] = b1 - sx*W1_x - sy*W1_y + vp[b,idx]@W1[2:] ----------
__global__ __launch_bounds__(64) void nystrom_prep(const float* __restrict__ v,
    const int* __restrict__ indices, const float* __restrict__ W1,
    const float* __restrict__ b1, float* __restrict__ u)
{
    int bs  = blockIdx.x;            // 0..B*S-1
    int b   = bs / S;
    int s   = bs % S;
    int hid = threadIdx.x;           // 0..63
    int idx = indices[s];
    float sx = (float)(idx & (WW - 1)) * (1.0f / (WW - 1));
    float sy = (float)(idx >> 6)       * (1.0f / (HH - 1));
    float acc = b1[hid] - sx * W1[hid] - sy * W1[HID + hid];
    const float* vb = v + (size_t)b * C_IN * J + idx;
    #pragma unroll
    for (int c = 0; c < C_IN; ++c) {
        acc += vb[c * J] * W1[(2 + c) * HID + hid];
    }
    u[((size_t)b * S + s) * HID + hid] = acc;
}

// ---------- kernel 2: T[b,h,n] = sum_s gelu(c_n + u[b,s,h]) ----------
// c_n = c0(h) + n*dc(h), knots spanning the exact reachable range of
// c = xj*w0 + yj*w1 with xj,yj in [0,1].
__global__ __launch_bounds__(256) void nystrom_table(const float* __restrict__ u,
    const float* __restrict__ W1, float* __restrict__ T)
{
    __shared__ float us[S];
    int blk = blockIdx.x;            // b*HID + h
    int b   = blk >> 6;
    int h   = blk & 63;
    int n   = threadIdx.x;           // 0..255 = knot index

    us[n] = u[((size_t)b * S + n) * HID + h];
    __syncthreads();

    float w0 = W1[h], w1 = W1[HID + h];
    float c0 = fminf(w0, 0.0f) + fminf(w1, 0.0f);
    float c1 = fmaxf(w0, 0.0f) + fmaxf(w1, 0.0f);
    float dc = fmaxf(c1 - c0, 1e-6f) * (1.0f / (TN - 1));
    float cn = c0 + (float)n * dc;

    float acc = 0.0f;
    #pragma unroll 4
    for (int s = 0; s < S; ++s) {
        float x = cn + us[s];                      // LDS broadcast read
        float p = __builtin_fmaf(-GELU_B, x * x, -GELU_A);
        float e = __builtin_amdgcn_exp2f(p * x);
        acc = __builtin_fmaf(x, __builtin_amdgcn_rcpf(e + 1.0f), acc);
    }
    T[(size_t)blk * TN + n] = acc;
}

// ---------- kernel 3: interp + W2 epilogue ----------
__global__ __launch_bounds__(256) void nystrom_eval(const float* __restrict__ T,
    const float* __restrict__ W1, const float* __restrict__ W2,
    const float* __restrict__ b2, float* __restrict__ out)
{
    __shared__ float Tl[HID][TN + 1];   // padded: stride 257 -> conflict-free gathers
    __shared__ float G[JT3][HID + 1];
    int tid = threadIdx.x;
    int blk = blockIdx.x;               // b*(J/JT3) + tile
    int b   = blk >> 7;                 // J/JT3 = 128
    int j0  = (blk & 127) * JT3;

    // stage this batch's table (64 KB) into LDS, float4 loads
    const float4* Tb4 = (const float4*)(T + (size_t)b * HID * TN);
    #pragma unroll
    for (int k = tid; k < HID * TN / 4; k += 256) {
        float4 vv = Tb4[k];
        int h = k >> 6;                 // 64 float4 per table row
        int n = (k & 63) * 4;
        Tl[h][n] = vv.x; Tl[h][n+1] = vv.y; Tl[h][n+2] = vv.z; Tl[h][n+3] = vv.w;
    }
    __syncthreads();

    // interp: thread -> (j = j0 + tid&31, h = (tid>>5) + 8k)
    int jl = tid & 31;
    int j  = j0 + jl;
    float xj = (float)(j & (WW - 1)) * (1.0f / (WW - 1));
    float yj = (float)(j >> 6)       * (1.0f / (HH - 1));
    #pragma unroll
    for (int k = 0; k < 8; ++k) {
        int h = (tid >> 5) + k * 8;
        float w0 = W1[h], w1 = W1[HID + h];
        float c0 = fminf(w0, 0.0f) + fminf(w1, 0.0f);
        float c1 = fmaxf(w0, 0.0f) + fmaxf(w1, 0.0f);
        float inv = (float)(TN - 1) / fmaxf(c1 - c0, 1e-6f);
        float c = xj * w0 + yj * w1;
        float t = (c - c0) * inv;
        int i = (int)t;
        i = max(0, min(TN - 2, i));
        float f = t - (float)i;
        float t0 = Tl[h][i], t1 = Tl[h][i + 1];
        G[jl][h] = __builtin_fmaf(f, t1 - t0, t0);
    }
    __syncthreads();

    // epilogue: out[b,co,j0+jj] = (1/S)*sum_h G[jj][h]*W2[h,co] + b2[co]
    int co = tid & 31;
    #pragma unroll
    for (int q = 0; q < 4; ++q) {
        int jj = (tid >> 5) * 4 + q;
        float sum = 0.0f;
        #pragma unroll
        for (int h = 0; h < HID; ++h) {
            sum = __builtin_fmaf(G[jj][h], W2[h * C_OUT + co], sum);
        }
        out[(size_t)b * C_OUT * J + (size_t)co * J + j0 + jj] = sum * (1.0f / S) + b2[co];
    }
}

extern "C" void kernel_launch(void* const* d_in, const int* in_sizes, int n_in,
                              void* d_out, int out_size, void* d_ws, size_t ws_size,
                              hipStream_t stream) {
    const float* v       = (const float*)d_in[0];
    const int*   indices = (const int*)  d_in[1];
    const float* W1      = (const float*)d_in[2];
    const float* b1      = (const float*)d_in[3];
    const float* W2      = (const float*)d_in[4];
    const float* b2      = (const float*)d_in[5];
    float* out = (float*)d_out;
    float* u   = (float*)d_ws;                       // B*S*HID*4   = 128 KB
    float* T   = (float*)d_ws + (size_t)BB * S * HID; // B*HID*TN*4 = 128 KB

    hipLaunchKernelGGL(nystrom_prep,  dim3(BB * S),        dim3(64),  0, stream,
                       v, indices, W1, b1, u);
    hipLaunchKernelGGL(nystrom_table, dim3(BB * HID),      dim3(TN),  0, stream,
                       u, W1, T);
    hipLaunchKernelGGL(nystrom_eval,  dim3(BB * (J / JT3)), dim3(256), 0, stream,
                       T, W1, W2, b2, out);
}